// Round 9
// baseline (3160.158 us; speedup 1.0000x reference)
//
#include <hip/hip_runtime.h>
#include <hip/hip_fp16.h>
#include <math.h>

#define BB   8
#define CIN  64
#define COUT 64
#define HH   128
#define WW   128
#define HW   (HH*WW)

typedef unsigned short u16;
typedef _Float16 f16;
typedef __attribute__((ext_vector_type(8))) f16   f16x8;
typedef __attribute__((ext_vector_type(4))) float f32x4;

// ---------------------------------------------------------------------------
// K0b: weight prep. Wd16[k][o][c] from w_def[o][c][k]. (scalar, simple)
// ---------------------------------------------------------------------------
__global__ __launch_bounds__(256) void k_wprep(const float* __restrict__ w_def,
                                               u16* __restrict__ Wd16)
{
  const int i = blockIdx.x*256 + threadIdx.x;   // 144 blocks * 256 = 36864 exact
  const int k = i >> 12, o = (i >> 6) & 63, c = i & 63;
  Wd16[i] = __half_as_ushort(__float2half_rn(w_def[(o*64 + c)*9 + k]));
}

// ---------------------------------------------------------------------------
// K1: offset conv — ROUND-1 PROVEN fp32 kernel (verbatim).
// ---------------------------------------------------------------------------
__global__ __launch_bounds__(256) void k_offconv(
    const float* __restrict__ x, const float* __restrict__ w_off,
    const float* __restrict__ b_off, float* __restrict__ off)
{
  __shared__ float wl[CIN*9*20];   // 46080 B
  __shared__ float tile[18*18];
  const int tid = threadIdx.x;
  for (int i = tid; i < CIN*9*18; i += 256) {
    int c = i / 162, r = i % 162;
    int t = r / 18, oc = r % 18;
    wl[(c*9 + t)*20 + oc] = w_off[(oc*CIN + c)*9 + t];
  }
  const int blk = blockIdx.x;
  const int b = blk >> 6;               // 64 tiles per image
  const int tile_id = blk & 63;
  const int h0 = (tile_id >> 3) << 4;
  const int w0 = (tile_id & 7) << 4;
  const int ty = tid >> 4, tx = tid & 15;
  float acc[18];
#pragma unroll
  for (int i = 0; i < 18; ++i) acc[i] = 0.f;
  const float* xb = x + (size_t)b*CIN*HW;
  for (int c = 0; c < CIN; ++c) {
    const float* xc = xb + c*HW;
    __syncthreads();                    // protect tile/wl from prior reads
    for (int i = tid; i < 18*18; i += 256) {
      int r = i / 18, q = i % 18;
      int gy = h0 - 1 + r, gx = w0 - 1 + q;
      tile[i] = (gy >= 0 && gy < HH && gx >= 0 && gx < WW) ? xc[gy*WW + gx] : 0.f;
    }
    __syncthreads();
#pragma unroll
    for (int t = 0; t < 9; ++t) {
      float xv = tile[(ty + t/3)*18 + (tx + t%3)];
      const float* wt = &wl[(c*9 + t)*20];
      float4 a0 = *(const float4*)(wt + 0);
      float4 a1 = *(const float4*)(wt + 4);
      float4 a2 = *(const float4*)(wt + 8);
      float4 a3 = *(const float4*)(wt + 12);
      float2 a4 = *(const float2*)(wt + 16);
      acc[0]  = fmaf(xv, a0.x, acc[0]);
      acc[1]  = fmaf(xv, a0.y, acc[1]);
      acc[2]  = fmaf(xv, a0.z, acc[2]);
      acc[3]  = fmaf(xv, a0.w, acc[3]);
      acc[4]  = fmaf(xv, a1.x, acc[4]);
      acc[5]  = fmaf(xv, a1.y, acc[5]);
      acc[6]  = fmaf(xv, a1.z, acc[6]);
      acc[7]  = fmaf(xv, a1.w, acc[7]);
      acc[8]  = fmaf(xv, a2.x, acc[8]);
      acc[9]  = fmaf(xv, a2.y, acc[9]);
      acc[10] = fmaf(xv, a2.z, acc[10]);
      acc[11] = fmaf(xv, a2.w, acc[11]);
      acc[12] = fmaf(xv, a3.x, acc[12]);
      acc[13] = fmaf(xv, a3.y, acc[13]);
      acc[14] = fmaf(xv, a3.z, acc[14]);
      acc[15] = fmaf(xv, a3.w, acc[15]);
      acc[16] = fmaf(xv, a4.x, acc[16]);
      acc[17] = fmaf(xv, a4.y, acc[17]);
    }
  }
  const int p = (h0 + ty)*WW + (w0 + tx);
  float* ob = off + (size_t)b*18*HW + p;
#pragma unroll
  for (int oc = 0; oc < 18; ++oc) ob[oc*HW] = acc[oc] + b_off[oc];
}

// ---------------------------------------------------------------------------
// K2 (DIAGNOSTIC v2): samples DIRECTLY from fp32 NCHW x with round-1's exact
// scalar bilinear expression; LINEAR (unswizzled) Sl/Wl with scalar writes;
// VALU dot-product compute with f16x8 linear LDS reads; round-6/8 epilogue.
// Splits {k_xpose + packed-f16 gather + swizzle} from {epilogue/Wd16/stats}.
// ---------------------------------------------------------------------------
__global__ __launch_bounds__(256) void k_deform_diag(const float* __restrict__ x,
    const float* __restrict__ off, const u16* __restrict__ Wd16,
    const float* __restrict__ b_def, float* __restrict__ pre)
{
  __shared__ u16 Sl[128*64];   // 16 KB, [px][c] LINEAR
  __shared__ u16 Wl[64*64];    //  8 KB, [o][c] LINEAR
  const int tid = threadIdx.x;
  const int b = blockIdx.x >> 7, y = blockIdx.x & 127;
  const int lane = tid & 63, wid = tid >> 6;
  const int pxq = lane & 15, kg = lane >> 4;
  const int spx = tid >> 1, cg = tid & 1;    // sampling: pixel, channel-half
  f32x4 acc[4][2];
#pragma unroll
  for (int a = 0; a < 4; ++a)
#pragma unroll
    for (int q = 0; q < 2; ++q) acc[a][q] = (f32x4)0.f;
  const float* xb = x + (size_t)b*CIN*HW;
  const float* offp = off + (size_t)b*18*HW + y*WW + spx;
  float dy = offp[0], dx = offp[HW];

  for (int k = 0; k < 9; ++k) {
    __syncthreads();             // Sl/Wl free (prev reads done)
    // stage Wl for tap k: 4096 u16, scalar, linear
    for (int t = tid; t < 64*64; t += 256)
      Wl[t] = Wd16[k*4096 + t];
    { // sample 32 channels of pixel spx at tap k — round-1 PROVEN fp32 math
      const float ys = (float)(y - 1 + k/3) + dy;
      const float xs = (float)(spx - 1 + k%3) + dx;
      const float y0f = floorf(ys), x0f = floorf(xs);
      const float tyf = ys - y0f, txf = xs - x0f;
      const float wy0 = 1.f - tyf, wx0 = 1.f - txf;
      float w00 = wy0*wx0, w01 = wy0*txf, w10 = tyf*wx0, w11 = tyf*txf;
      const bool vy0 = (y0f >=  0.f) && (y0f <= 127.f);
      const bool vy1 = (y0f >= -1.f) && (y0f <= 126.f);
      const bool vx0 = (x0f >=  0.f) && (x0f <= 127.f);
      const bool vx1 = (x0f >= -1.f) && (x0f <= 126.f);
      w00 = (vy0 && vx0) ? w00 : 0.f;
      w01 = (vy0 && vx1) ? w01 : 0.f;
      w10 = (vy1 && vx0) ? w10 : 0.f;
      w11 = (vy1 && vx1) ? w11 : 0.f;
      const int yi0 = (int)fminf(fmaxf(y0f,       0.f), 127.f);
      const int yi1 = (int)fminf(fmaxf(y0f + 1.f, 0.f), 127.f);
      const int xi0 = (int)fminf(fmaxf(x0f,       0.f), 127.f);
      const int xi1 = (int)fminf(fmaxf(x0f + 1.f, 0.f), 127.f);
      const int o00 = yi0*WW + xi0, o01 = yi0*WW + xi1;
      const int o10 = yi1*WW + xi0, o11 = yi1*WW + xi1;
      const float* xc = xb + cg*32*HW;
      u16* srow = Sl + spx*64 + cg*32;
#pragma unroll 8
      for (int ci = 0; ci < 32; ++ci) {
        float v = w00*xc[o00] + w01*xc[o01] + w10*xc[o10] + w11*xc[o11];
        srow[ci] = __half_as_ushort(__float2half_rn(v));
        xc += HW;
      }
    }
    if (k < 8) { dy = offp[(2*k + 2)*HW]; dx = offp[(2*k + 3)*HW]; }
    __syncthreads();             // Sl/Wl ready
    // ---- VALU dot-product phase, linear f16x8 LDS reads ----
#pragma unroll
    for (int ch = 0; ch < 8; ++ch) {
      f16x8 Sv0 = *(const f16x8*)(Sl + (wid*32 +  0 + pxq)*64 + ch*8);
      f16x8 Sv1 = *(const f16x8*)(Sl + (wid*32 + 16 + pxq)*64 + ch*8);
#pragma unroll
      for (int mt = 0; mt < 4; ++mt) {
#pragma unroll
        for (int j = 0; j < 4; ++j) {
          const f16x8 Wv = *(const f16x8*)(Wl + (mt*16 + kg*4 + j)*64 + ch*8);
          float s0 = 0.f, s1 = 0.f;
#pragma unroll
          for (int q = 0; q < 8; ++q) {
            s0 += (float)Sv0[q] * (float)Wv[q];
            s1 += (float)Sv1[q] * (float)Wv[q];
          }
          acc[mt][0][j] += s0;
          acc[mt][1][j] += s1;
        }
      }
    }
  }
  // ---- epilogue: bias + coalesced pre-BN store (identical to rounds 6/8) ----
  const int pxbase = y*WW + wid*32 + pxq;
#pragma unroll
  for (int mt = 0; mt < 4; ++mt)
#pragma unroll
    for (int j = 0; j < 4; ++j) {
      const int o = mt*16 + kg*4 + j;
      const float bd = b_def[o];
      pre[(size_t)(b*COUT + o)*HW + pxbase]      = acc[mt][0][j] + bd;
      pre[(size_t)(b*COUT + o)*HW + pxbase + 16] = acc[mt][1][j] + bd;
    }
}

// ---------------------------------------------------------------------------
// K2b: BN stats pass. Block = (channel o, image b); sums 16384 elements.
// ---------------------------------------------------------------------------
__global__ __launch_bounds__(256) void k_stats(const float* __restrict__ pre,
                                               float* __restrict__ stats)
{
  __shared__ float red[8];
  const int o = blockIdx.x >> 3, b = blockIdx.x & 7;
  const float* p = pre + (size_t)(b*COUT + o)*HW;
  const int tid = threadIdx.x;
  float s1 = 0.f, s2 = 0.f;
  for (int i = tid; i < HW/4; i += 256) {
    float4 v = ((const float4*)p)[i];
    s1 += (v.x + v.y) + (v.z + v.w);
    s2 += (v.x*v.x + v.y*v.y) + (v.z*v.z + v.w*v.w);
  }
#pragma unroll
  for (int d = 32; d >= 1; d >>= 1) {
    s1 += __shfl_down(s1, d, 64);
    s2 += __shfl_down(s2, d, 64);
  }
  const int wid = tid >> 6, lane = tid & 63;
  if (lane == 0) { red[wid*2] = s1; red[wid*2 + 1] = s2; }
  __syncthreads();
  if (tid == 0) {
    atomicAdd(&stats[o*2 + 0], red[0] + red[2] + red[4] + red[6]);
    atomicAdd(&stats[o*2 + 1], red[1] + red[3] + red[5] + red[7]);
  }
}

// ---------------------------------------------------------------------------
// K3: BN finalize + gamma/beta + ReLU, float4-wide, IN PLACE on d_out.
// ---------------------------------------------------------------------------
__global__ __launch_bounds__(256) void k_bn(
    const float* __restrict__ stats, const float* __restrict__ gamma,
    const float* __restrict__ beta, float* __restrict__ out)
{
  const int i = blockIdx.x*256 + threadIdx.x;     // float4 index
  const int o = (i >> 12) & 63;
  const float inv_n = 1.f / (float)(BB*HW);
  const float mean = stats[2*o] * inv_n;
  const float var  = stats[2*o + 1] * inv_n - mean*mean;
  const float sc = rsqrtf(var + 1e-5f) * gamma[o];
  const float sh = fmaf(-mean, sc, beta[o]);
  float4 v = ((float4*)out)[i];
  v.x = fmaxf(fmaf(v.x, sc, sh), 0.f);
  v.y = fmaxf(fmaf(v.y, sc, sh), 0.f);
  v.z = fmaxf(fmaf(v.z, sc, sh), 0.f);
  v.w = fmaxf(fmaf(v.w, sc, sh), 0.f);
  ((float4*)out)[i] = v;
}

extern "C" void kernel_launch(void* const* d_in, const int* in_sizes, int n_in,
                              void* d_out, int out_size, void* d_ws, size_t ws_size,
                              hipStream_t stream)
{
  const float* x     = (const float*)d_in[0];
  const float* w_off = (const float*)d_in[1];
  const float* b_off = (const float*)d_in[2];
  const float* w_def = (const float*)d_in[3];
  const float* b_def = (const float*)d_in[4];
  const float* gamma = (const float*)d_in[5];
  const float* beta  = (const float*)d_in[6];
  float* out = (float*)d_out;

  u16*   Wd16  = (u16*)d_ws;                    // 36,864 u16 (73,728 B)
  float* off   = (float*)(Wd16 + 9*64*64);      // 2,359,296 f32 (9.44 MB)
  float* stats = off + (size_t)BB*18*HW;        // 128 f32  (total ~9.5 MB)

  hipMemsetAsync(stats, 0, 128*sizeof(float), stream);
  hipLaunchKernelGGL(k_wprep,       dim3(144),  dim3(256), 0, stream, w_def, Wd16);
  hipLaunchKernelGGL(k_offconv,     dim3(512),  dim3(256), 0, stream, x, w_off, b_off, off);
  hipLaunchKernelGGL(k_deform_diag, dim3(1024), dim3(256), 0, stream, x, off, Wd16, b_def, out);
  hipLaunchKernelGGL(k_stats,       dim3(512),  dim3(256), 0, stream, out, stats);
  hipLaunchKernelGGL(k_bn,          dim3(8192), dim3(256), 0, stream, stats, gamma, beta, out);
}

// Round 10
// 385.606 us; speedup vs baseline: 8.1953x; 8.1953x over previous
//
#include <hip/hip_runtime.h>
#include <hip/hip_fp16.h>
#include <math.h>

#define BB   8
#define CIN  64
#define COUT 64
#define HH   128
#define WW   128
#define HW   (HH*WW)

#define SLP  72   // padded LDS row stride (u16): 144 B = 9*16 B, breaks bank uniformity

typedef unsigned short u16;
typedef _Float16 f16;
typedef __attribute__((ext_vector_type(8))) f16   f16x8;
typedef __attribute__((ext_vector_type(4))) float f32x4;

// ---------------------------------------------------------------------------
// K0b: weight prep. Wd16[k][o][c] from w_def[o][c][k]. (scalar, proven r9)
// ---------------------------------------------------------------------------
__global__ __launch_bounds__(256) void k_wprep(const float* __restrict__ w_def,
                                               u16* __restrict__ Wd16)
{
  const int i = blockIdx.x*256 + threadIdx.x;   // 144 blocks * 256 = 36864 exact
  const int k = i >> 12, o = (i >> 6) & 63, c = i & 63;
  Wd16[i] = __half_as_ushort(__float2half_rn(w_def[(o*64 + c)*9 + k]));
}

// ---------------------------------------------------------------------------
// K1: offset conv — ROUND-1 PROVEN fp32 kernel (verbatim).
// ---------------------------------------------------------------------------
__global__ __launch_bounds__(256) void k_offconv(
    const float* __restrict__ x, const float* __restrict__ w_off,
    const float* __restrict__ b_off, float* __restrict__ off)
{
  __shared__ float wl[CIN*9*20];   // 46080 B
  __shared__ float tile[18*18];
  const int tid = threadIdx.x;
  for (int i = tid; i < CIN*9*18; i += 256) {
    int c = i / 162, r = i % 162;
    int t = r / 18, oc = r % 18;
    wl[(c*9 + t)*20 + oc] = w_off[(oc*CIN + c)*9 + t];
  }
  const int blk = blockIdx.x;
  const int b = blk >> 6;               // 64 tiles per image
  const int tile_id = blk & 63;
  const int h0 = (tile_id >> 3) << 4;
  const int w0 = (tile_id & 7) << 4;
  const int ty = tid >> 4, tx = tid & 15;
  float acc[18];
#pragma unroll
  for (int i = 0; i < 18; ++i) acc[i] = 0.f;
  const float* xb = x + (size_t)b*CIN*HW;
  for (int c = 0; c < CIN; ++c) {
    const float* xc = xb + c*HW;
    __syncthreads();                    // protect tile/wl from prior reads
    for (int i = tid; i < 18*18; i += 256) {
      int r = i / 18, q = i % 18;
      int gy = h0 - 1 + r, gx = w0 - 1 + q;
      tile[i] = (gy >= 0 && gy < HH && gx >= 0 && gx < WW) ? xc[gy*WW + gx] : 0.f;
    }
    __syncthreads();
#pragma unroll
    for (int t = 0; t < 9; ++t) {
      float xv = tile[(ty + t/3)*18 + (tx + t%3)];
      const float* wt = &wl[(c*9 + t)*20];
      float4 a0 = *(const float4*)(wt + 0);
      float4 a1 = *(const float4*)(wt + 4);
      float4 a2 = *(const float4*)(wt + 8);
      float4 a3 = *(const float4*)(wt + 12);
      float2 a4 = *(const float2*)(wt + 16);
      acc[0]  = fmaf(xv, a0.x, acc[0]);
      acc[1]  = fmaf(xv, a0.y, acc[1]);
      acc[2]  = fmaf(xv, a0.z, acc[2]);
      acc[3]  = fmaf(xv, a0.w, acc[3]);
      acc[4]  = fmaf(xv, a1.x, acc[4]);
      acc[5]  = fmaf(xv, a1.y, acc[5]);
      acc[6]  = fmaf(xv, a1.z, acc[6]);
      acc[7]  = fmaf(xv, a1.w, acc[7]);
      acc[8]  = fmaf(xv, a2.x, acc[8]);
      acc[9]  = fmaf(xv, a2.y, acc[9]);
      acc[10] = fmaf(xv, a2.z, acc[10]);
      acc[11] = fmaf(xv, a2.w, acc[11]);
      acc[12] = fmaf(xv, a3.x, acc[12]);
      acc[13] = fmaf(xv, a3.y, acc[13]);
      acc[14] = fmaf(xv, a3.z, acc[14]);
      acc[15] = fmaf(xv, a3.w, acc[15]);
      acc[16] = fmaf(xv, a4.x, acc[16]);
      acc[17] = fmaf(xv, a4.y, acc[17]);
    }
  }
  const int p = (h0 + ty)*WW + (w0 + tx);
  float* ob = off + (size_t)b*18*HW + p;
#pragma unroll
  for (int oc = 0; oc < 18; ++oc) ob[oc*HW] = acc[oc] + b_off[oc];
}

// ---------------------------------------------------------------------------
// K2: r9-PROVEN sampling (fp32 NCHW scalar bilinear) + padded-linear LDS +
//     MFMA einsum (equivalence-proven vs the r9 VALU dot product) + r9 epilogue.
// ---------------------------------------------------------------------------
__global__ __launch_bounds__(256) void k_deform16b(const float* __restrict__ x,
    const float* __restrict__ off, const u16* __restrict__ Wd16,
    const float* __restrict__ b_def, float* __restrict__ pre)
{
  __shared__ u16 Sl[128*SLP];   // 18 KB, [px][c] padded-linear
  __shared__ u16 Wl[64*SLP];    //  9 KB, [o][c] padded-linear
  const int tid = threadIdx.x;
  const int b = blockIdx.x >> 7, y = blockIdx.x & 127;
  const int lane = tid & 63, wid = tid >> 6;
  const int pxq = lane & 15, kg = lane >> 4;
  const int spx = tid >> 1, cg = tid & 1;    // sampling: pixel, channel-half
  f32x4 acc[4][2];
#pragma unroll
  for (int a = 0; a < 4; ++a)
#pragma unroll
    for (int q = 0; q < 2; ++q) acc[a][q] = (f32x4)0.f;
  const float* xb = x + (size_t)b*CIN*HW;
  const float* offp = off + (size_t)b*18*HW + y*WW + spx;
  float dy = offp[0], dx = offp[HW];

  for (int k = 0; k < 9; ++k) {
    __syncthreads();             // Sl/Wl free (prev reads done)
    // stage Wl for tap k: 4096 u16, scalar, padded-linear
    for (int t = tid; t < 64*64; t += 256)
      Wl[(t >> 6)*SLP + (t & 63)] = Wd16[k*4096 + t];
    { // sample 32 channels of pixel spx at tap k — r9 PROVEN fp32 math
      const float ys = (float)(y - 1 + k/3) + dy;
      const float xs = (float)(spx - 1 + k%3) + dx;
      const float y0f = floorf(ys), x0f = floorf(xs);
      const float tyf = ys - y0f, txf = xs - x0f;
      const float wy0 = 1.f - tyf, wx0 = 1.f - txf;
      float w00 = wy0*wx0, w01 = wy0*txf, w10 = tyf*wx0, w11 = tyf*txf;
      const bool vy0 = (y0f >=  0.f) && (y0f <= 127.f);
      const bool vy1 = (y0f >= -1.f) && (y0f <= 126.f);
      const bool vx0 = (x0f >=  0.f) && (x0f <= 127.f);
      const bool vx1 = (x0f >= -1.f) && (x0f <= 126.f);
      w00 = (vy0 && vx0) ? w00 : 0.f;
      w01 = (vy0 && vx1) ? w01 : 0.f;
      w10 = (vy1 && vx0) ? w10 : 0.f;
      w11 = (vy1 && vx1) ? w11 : 0.f;
      const int yi0 = (int)fminf(fmaxf(y0f,       0.f), 127.f);
      const int yi1 = (int)fminf(fmaxf(y0f + 1.f, 0.f), 127.f);
      const int xi0 = (int)fminf(fmaxf(x0f,       0.f), 127.f);
      const int xi1 = (int)fminf(fmaxf(x0f + 1.f, 0.f), 127.f);
      const int o00 = yi0*WW + xi0, o01 = yi0*WW + xi1;
      const int o10 = yi1*WW + xi0, o11 = yi1*WW + xi1;
      const float* xc = xb + cg*32*HW;
      u16* srow = Sl + spx*SLP + cg*32;
#pragma unroll 4
      for (int ci = 0; ci < 32; ++ci) {
        float v = w00*xc[o00] + w01*xc[o01] + w10*xc[o10] + w11*xc[o11];
        srow[ci] = __half_as_ushort(__float2half_rn(v));
        xc += HW;
      }
    }
    if (k < 8) { dy = offp[(2*k + 2)*HW]; dx = offp[(2*k + 3)*HW]; }
    __syncthreads();             // Sl/Wl ready
    // ---- MFMA phase (fragment algebra identical to r8, padded-linear LDS) ----
#pragma unroll
    for (int ks = 0; ks < 2; ++ks) {
      f16x8 Af[4], Bf[2];
#pragma unroll
      for (int mt = 0; mt < 4; ++mt)
        Af[mt] = *(const f16x8*)(Wl + (mt*16 + pxq)*SLP + (ks*4 + kg)*8);
#pragma unroll
      for (int nt = 0; nt < 2; ++nt)
        Bf[nt] = *(const f16x8*)(Sl + (wid*32 + nt*16 + pxq)*SLP + (ks*4 + kg)*8);
#pragma unroll
      for (int mt = 0; mt < 4; ++mt)
#pragma unroll
        for (int nt = 0; nt < 2; ++nt)
          acc[mt][nt] = __builtin_amdgcn_mfma_f32_16x16x32_f16(
              Af[mt], Bf[nt], acc[mt][nt], 0, 0, 0);
    }
  }
  // ---- epilogue: bias + coalesced pre-BN store (r9-proven mapping) ----
  const int pxbase = y*WW + wid*32 + pxq;
#pragma unroll
  for (int mt = 0; mt < 4; ++mt)
#pragma unroll
    for (int j = 0; j < 4; ++j) {
      const int o = mt*16 + kg*4 + j;
      const float bd = b_def[o];
      pre[(size_t)(b*COUT + o)*HW + pxbase]      = acc[mt][0][j] + bd;
      pre[(size_t)(b*COUT + o)*HW + pxbase + 16] = acc[mt][1][j] + bd;
    }
}

// ---------------------------------------------------------------------------
// K2b: BN stats pass (r9-proven). Block = (channel o, image b).
// ---------------------------------------------------------------------------
__global__ __launch_bounds__(256) void k_stats(const float* __restrict__ pre,
                                               float* __restrict__ stats)
{
  __shared__ float red[8];
  const int o = blockIdx.x >> 3, b = blockIdx.x & 7;
  const float* p = pre + (size_t)(b*COUT + o)*HW;
  const int tid = threadIdx.x;
  float s1 = 0.f, s2 = 0.f;
  for (int i = tid; i < HW/4; i += 256) {
    float4 v = ((const float4*)p)[i];
    s1 += (v.x + v.y) + (v.z + v.w);
    s2 += (v.x*v.x + v.y*v.y) + (v.z*v.z + v.w*v.w);
  }
#pragma unroll
  for (int d = 32; d >= 1; d >>= 1) {
    s1 += __shfl_down(s1, d, 64);
    s2 += __shfl_down(s2, d, 64);
  }
  const int wid = tid >> 6, lane = tid & 63;
  if (lane == 0) { red[wid*2] = s1; red[wid*2 + 1] = s2; }
  __syncthreads();
  if (tid == 0) {
    atomicAdd(&stats[o*2 + 0], red[0] + red[2] + red[4] + red[6]);
    atomicAdd(&stats[o*2 + 1], red[1] + red[3] + red[5] + red[7]);
  }
}

// ---------------------------------------------------------------------------
// K3: BN finalize + gamma/beta + ReLU, float4-wide, IN PLACE on d_out (r9-proven).
// ---------------------------------------------------------------------------
__global__ __launch_bounds__(256) void k_bn(
    const float* __restrict__ stats, const float* __restrict__ gamma,
    const float* __restrict__ beta, float* __restrict__ out)
{
  const int i = blockIdx.x*256 + threadIdx.x;     // float4 index
  const int o = (i >> 12) & 63;
  const float inv_n = 1.f / (float)(BB*HW);
  const float mean = stats[2*o] * inv_n;
  const float var  = stats[2*o + 1] * inv_n - mean*mean;
  const float sc = rsqrtf(var + 1e-5f) * gamma[o];
  const float sh = fmaf(-mean, sc, beta[o]);
  float4 v = ((float4*)out)[i];
  v.x = fmaxf(fmaf(v.x, sc, sh), 0.f);
  v.y = fmaxf(fmaf(v.y, sc, sh), 0.f);
  v.z = fmaxf(fmaf(v.z, sc, sh), 0.f);
  v.w = fmaxf(fmaf(v.w, sc, sh), 0.f);
  ((float4*)out)[i] = v;
}

extern "C" void kernel_launch(void* const* d_in, const int* in_sizes, int n_in,
                              void* d_out, int out_size, void* d_ws, size_t ws_size,
                              hipStream_t stream)
{
  const float* x     = (const float*)d_in[0];
  const float* w_off = (const float*)d_in[1];
  const float* b_off = (const float*)d_in[2];
  const float* w_def = (const float*)d_in[3];
  const float* b_def = (const float*)d_in[4];
  const float* gamma = (const float*)d_in[5];
  const float* beta  = (const float*)d_in[6];
  float* out = (float*)d_out;

  u16*   Wd16  = (u16*)d_ws;                    // 36,864 u16 (73,728 B)
  float* off   = (float*)(Wd16 + 9*64*64);      // 2,359,296 f32 (9.44 MB)
  float* stats = off + (size_t)BB*18*HW;        // 128 f32  (total ~9.5 MB)

  hipMemsetAsync(stats, 0, 128*sizeof(float), stream);
  hipLaunchKernelGGL(k_wprep,      dim3(144),  dim3(256), 0, stream, w_def, Wd16);
  hipLaunchKernelGGL(k_offconv,    dim3(512),  dim3(256), 0, stream, x, w_off, b_off, off);
  hipLaunchKernelGGL(k_deform16b,  dim3(1024), dim3(256), 0, stream, x, off, Wd16, b_def, out);
  hipLaunchKernelGGL(k_stats,      dim3(512),  dim3(256), 0, stream, out, stats);
  hipLaunchKernelGGL(k_bn,         dim3(8192), dim3(256), 0, stream, stats, gamma, beta, out);
}